// Round 13
// baseline (897.364 us; speedup 1.0000x reference)
//
#include <hip/hip_runtime.h>
#include <hip/hip_cooperative_groups.h>
namespace cg = cooperative_groups;

// HeteroGNN on MI355X. Inputs/weights/output fp32 (per reference); intermediates bf16.
// Round 21: cooperative fusion of the graph-prep pipeline.
//  - R20: fine buckets WIN (342.6->336.3, rest 200.5). k_mega floor re-confirmed
//    (135.8us, stable across TLP/VALU/ILP/L2 experiments). Untouched this round.
//  - Rest (~200us) models to ~80us of BW/latency floors; a large chunk is kernel
//    BOUNDARIES (teardown drain + ~4-8us launch, x6) on tiny graph kernels. Fuse
//    {memset, histogram, kb2 scatter, kb3 CSR} into ONE cooperative kernel k_graph
//    (1095 blk x 256 thr, grid.sync between phases; LDS 15.2KB -> 8 blk/CU ->
//    capacity 2048 >= 1095). bcnt/bcur/binE stay L2-hot. Launches 7 -> 4.
//  - Phase bodies are byte-identical ports of R20's passing kernels.
//   k_pre  : weights->bf16 WT[n][k] | x->bf16 pools
//   k_graph: [coop] zero | histogram | bin scatter | per-bucket CSR
//   k_host : h=lrelu([mean(xfb nbrs)|xhb]@WT0_fh^T+b0); hT=h@WT1_l^T        (M=20000)
//   k_mega : h=lrelu([mean(xhb nbrs)|xfb]@WT0_hf^T+b0);
//            g=lrelu(h@WT1_r^T+mean(hT nbrs)+b1); out=g@WTo^T+bout          (M=200000)
// g_host dead in reference -> W1_fh_* unused.

#define N_HOST 20000
#define N_FLOW 200000
#define NEDGE  600000
#define D_IN   64
#define D_H    128
#define D_OUT  32
#define NSEG   (N_FLOW + N_HOST)
#define NBKT_F 782                 // 256-node flow buckets
#define NBKT_H 313                 // 64-node host buckets
#define NBKT   (NBKT_F + NBKT_H)   // 1095
#define NBKT_PAD 1100              // 5*220, scan padding
#define NEB    586                 // ceil(1200000/2048)

typedef unsigned short u16;
typedef unsigned int   u32;
typedef short bf16x8 __attribute__((ext_vector_type(8)));
typedef float f32x4  __attribute__((ext_vector_type(4)));
typedef float fx2    __attribute__((ext_vector_type(2)));
typedef unsigned int u32x4 __attribute__((ext_vector_type(4)));   // for nontemporal ld

__device__ __forceinline__ float bfh(u16 h) { return __uint_as_float(((u32)h) << 16); }
__device__ __forceinline__ u16 fbh(float f) {
    u32 u = __float_as_uint(f);
    return (u16)((u + 0x7fffu + ((u >> 16) & 1u)) >> 16);   // RNE
}
__device__ __forceinline__ u32 packbf(float x, float y) {
    return (u32)fbh(x) | ((u32)fbh(y) << 16);
}
// packed bf16 unpack+accumulate (v_pk_add_f32)
__device__ __forceinline__ void accp(fx2* a, uint4 u) {
    fx2 p;
    p.x = __uint_as_float(u.x << 16); p.y = __uint_as_float(u.x & 0xffff0000u); a[0] += p;
    p.x = __uint_as_float(u.y << 16); p.y = __uint_as_float(u.y & 0xffff0000u); a[1] += p;
    p.x = __uint_as_float(u.z << 16); p.y = __uint_as_float(u.z & 0xffff0000u); a[2] += p;
    p.x = __uint_as_float(u.w << 16); p.y = __uint_as_float(u.w & 0xffff0000u); a[3] += p;
}
__device__ __forceinline__ uint4 packp(const fx2* a, float inv) {
    uint4 o;
    o.x = packbf(a[0].x * inv, a[0].y * inv);
    o.y = packbf(a[1].x * inv, a[1].y * inv);
    o.z = packbf(a[2].x * inv, a[2].y * inv);
    o.w = packbf(a[3].x * inv, a[3].y * inv);
    return o;
}

// gather-mean of 16B chunks; neighbor indices from LDS window (fit) or global fallback.
template <int U>
__device__ __forceinline__ uint4 gmean(const u16* __restrict__ pool, int rs, int coff,
                                       const int* __restrict__ gcsr,
                                       const int* __restrict__ lcsr, int st0, bool fit,
                                       int st, int en) {
    fx2 a[4] = {};
    for (int e = st; e < en; e += U) {
        int n[U];
#pragma unroll
        for (int j = 0; j < U; j++)
            n[j] = (e + j < en) ? (fit ? lcsr[e + j - st0] : gcsr[e + j]) : -1;
        uint4 u[U];
#pragma unroll
        for (int j = 0; j < U; j++)
            u[j] = (n[j] >= 0) ? *(const uint4*)(pool + n[j] * rs + coff)
                               : make_uint4(0u, 0u, 0u, 0u);
#pragma unroll
        for (int j = 0; j < U; j++) accp(a, u[j]);
    }
    float inv = (en > st) ? 1.f / (float)(en - st) : 0.f;
    return packp(a, inv);
}

// ---------------- k_pre: weights transpose | x->bf16 (hist moved to k_graph) ----------------
__global__ void k_pre(const float* __restrict__ W0_hf_l, const float* __restrict__ W0_hf_r,
                      const float* __restrict__ W0_fh_l, const float* __restrict__ W0_fh_r,
                      const float* __restrict__ W1_l, const float* __restrict__ W1_r,
                      const float* __restrict__ Wout,
                      u16* __restrict__ WT0_hf, u16* __restrict__ WT0_fh,
                      u16* __restrict__ WT1_l, u16* __restrict__ WT1_r,
                      u16* __restrict__ WTo,
                      const float* __restrict__ xf, const float* __restrict__ xh,
                      u16* __restrict__ xfb, u16* __restrict__ xhb) {
    int b = blockIdx.x, t = threadIdx.x;
    if (b < 34) {
        u16 tmp[8];
        if (b < 32) {
            int e = (b & 7) * 2048 + t * 8;
            int n = e >> 7, k0 = e & 127;
            if (b < 8) {
#pragma unroll
                for (int j = 0; j < 8; j++) {
                    int k = k0 + j;
                    tmp[j] = fbh(k < 64 ? W0_hf_l[k * D_H + n] : W0_hf_r[(k - 64) * D_H + n]);
                }
                *(uint4*)(WT0_hf + n * 128 + k0) = *(uint4*)tmp;
            } else if (b < 16) {
#pragma unroll
                for (int j = 0; j < 8; j++) {
                    int k = k0 + j;
                    tmp[j] = fbh(k < 64 ? W0_fh_l[k * D_H + n] : W0_fh_r[(k - 64) * D_H + n]);
                }
                *(uint4*)(WT0_fh + n * 128 + k0) = *(uint4*)tmp;
            } else if (b < 24) {
#pragma unroll
                for (int j = 0; j < 8; j++) tmp[j] = fbh(W1_l[(k0 + j) * D_H + n]);
                *(uint4*)(WT1_l + n * 128 + k0) = *(uint4*)tmp;
            } else {
#pragma unroll
                for (int j = 0; j < 8; j++) tmp[j] = fbh(W1_r[(k0 + j) * D_H + n]);
                *(uint4*)(WT1_r + n * 128 + k0) = *(uint4*)tmp;
            }
        } else {
            int e = (b - 32) * 2048 + t * 8;
            int n = e >> 7, k0 = e & 127;
#pragma unroll
            for (int j = 0; j < 8; j++) tmp[j] = fbh(Wout[(k0 + j) * D_OUT + n]);
            *(uint4*)(WTo + n * 128 + k0) = *(uint4*)tmp;
        }
    } else {
        int q = (b - 34) * 256 + t;       // 8 floats per thread
        const int TF = (N_FLOW * D_IN) / 8;
        const int TT = TF + (N_HOST * D_IN) / 8;
        if (q >= TT) return;
        const float* src; u16* dst; int base;
        if (q < TF) { src = xf; dst = xfb; base = q * 8; }
        else        { src = xh; dst = xhb; base = (q - TF) * 8; }
        float4 f0 = *(const float4*)(src + base);
        float4 f1 = *(const float4*)(src + base + 4);
        uint4 o;
        o.x = packbf(f0.x, f0.y); o.y = packbf(f0.z, f0.w);
        o.z = packbf(f1.x, f1.y); o.w = packbf(f1.z, f1.w);
        *(uint4*)(dst + base) = o;
    }
}

// ---- k_graph [cooperative]: zero | histogram | bin scatter | per-bucket CSR ----
// 1095 blocks x 256 thr. LDS ~15.2KB -> 8 blk/CU (wave-limited) -> capacity 2048.
__global__ __launch_bounds__(256) void k_graph(
    const int* __restrict__ src_hf, const int* __restrict__ dst_hf,
    const int* __restrict__ src_fh, const int* __restrict__ dst_fh,
    int* __restrict__ bcnt, int* __restrict__ bcur,
    int2* __restrict__ binE, int* __restrict__ off, int* __restrict__ csr) {
    __shared__ int sh_h[NBKT];        // phase1 hist | phase2 lh
    __shared__ int sh_spx[NBKT_PAD];  // phase2 excl prefix | phase3 incl prefix
    __shared__ int sh_lb[NBKT];       // phase2 block base
    __shared__ int sh_ts[256];
    __shared__ int sh_deg[256];       // phase3 degree/cur
    cg::grid_group grid = cg::this_grid();
    const int b = blockIdx.x, t = threadIdx.x;

    // ---- phase 0: zero bcnt/bcur ----
    {
        int i = b * 256 + t;
        if (i < NBKT) { bcnt[i] = 0; bcur[i] = 0; }
    }
    __threadfence();
    grid.sync();

    // ---- phase 1: histogram (blocks 0..NEB-1) ----
    if (b < NEB) {
        for (int j = t; j < NBKT; j += 256) sh_h[j] = 0;
        __syncthreads();
        int base = b * 2048;
#pragma unroll
        for (int i = 0; i < 8; i++) {
            int e = base + t + i * 256;
            if (e < 2 * NEDGE) {
                int bkt = (e < NEDGE) ? (dst_hf[e] >> 8)
                                      : (NBKT_F + (dst_fh[e - NEDGE] >> 6));
                atomicAdd(&sh_h[bkt], 1);
            }
        }
        __syncthreads();
        for (int j = t; j < NBKT; j += 256)
            if (sh_h[j]) atomicAdd(&bcnt[j], sh_h[j]);
    }
    __threadfence();
    grid.sync();

    // ---- phase 2: bin scatter (blocks 0..NEB-1) ----
    if (b < NEB) {
        int v[5], loc[5];
        int b5 = t * 5, s = 0;
#pragma unroll
        for (int j = 0; j < 5; j++) {
            int idx = b5 + j;
            v[j] = (idx < NBKT) ? bcnt[idx] : 0;
            loc[j] = s; s += v[j];
        }
        sh_ts[t] = s;
        for (int j = t; j < NBKT; j += 256) sh_h[j] = 0;   // lh
        __syncthreads();
        for (int d = 1; d < 256; d <<= 1) {
            int x = (t >= d) ? sh_ts[t - d] : 0;
            __syncthreads();
            sh_ts[t] += x;
            __syncthreads();
        }
        int ex = sh_ts[t] - s;
#pragma unroll
        for (int j = 0; j < 5; j++) {
            int idx = b5 + j;
            if (idx < NBKT_PAD) sh_spx[idx] = ex + loc[j];
        }
        __syncthreads();
        int base = b * 2048;
        int mybkt[8], myrank[8], mysrc[8], mydst[8];
#pragma unroll
        for (int i = 0; i < 8; i++) {
            int e = base + t + i * 256;
            mybkt[i] = -1;
            if (e < 2 * NEDGE) {
                int sv, d;
                if (e < NEDGE) { sv = src_hf[e]; d = dst_hf[e]; }
                else           { sv = src_fh[e - NEDGE]; d = dst_fh[e - NEDGE] + N_FLOW; }
                int bkt = (d < N_FLOW) ? (d >> 8) : (NBKT_F + ((d - N_FLOW) >> 6));
                mybkt[i] = bkt; mysrc[i] = sv; mydst[i] = d;
                myrank[i] = atomicAdd(&sh_h[bkt], 1);
            }
        }
        __syncthreads();
        for (int j = t; j < NBKT; j += 256)
            sh_lb[j] = sh_h[j] ? atomicAdd(&bcur[j], sh_h[j]) : 0;
        __syncthreads();
#pragma unroll
        for (int i = 0; i < 8; i++) {
            if (mybkt[i] >= 0) {
                int pos = sh_spx[mybkt[i]] + sh_lb[mybkt[i]] + myrank[i];
                binE[pos] = make_int2(mysrc[i], mydst[i]);
            }
        }
    }
    __threadfence();
    grid.sync();

    // ---- phase 3: per-bucket CSR (all 1095 blocks) ----
    {
        int v[5], iv[5];
        int b5 = t * 5, s = 0;
#pragma unroll
        for (int j = 0; j < 5; j++) {
            int idx = b5 + j;
            v[j] = (idx < NBKT) ? bcnt[idx] : 0;
            s += v[j]; iv[j] = s;
        }
        sh_ts[t] = s;
        __syncthreads();
        for (int d = 1; d < 256; d <<= 1) {
            int x = (t >= d) ? sh_ts[t - d] : 0;
            __syncthreads();
            sh_ts[t] += x;
            __syncthreads();
        }
        int ex = sh_ts[t] - s;
#pragma unroll
        for (int j = 0; j < 5; j++) {
            int idx = b5 + j;
            if (idx < NBKT_PAD) sh_spx[idx] = ex + iv[j];   // inclusive prefix
        }
        sh_deg[t] = 0;
        __syncthreads();
        int e0 = (b == 0) ? 0 : sh_spx[b - 1];
        int e1 = sh_spx[b];
        int nbase, ncnt;
        if (b < NBKT_F) { nbase = b << 8; ncnt = min(256, N_FLOW - nbase); }
        else { int hb = b - NBKT_F; nbase = N_FLOW + (hb << 6); ncnt = min(64, NSEG - nbase); }
        for (int e = e0 + t; e < e1; e += 256) {
            int2 p = binE[e];
            atomicAdd(&sh_deg[p.y - nbase], 1);
        }
        __syncthreads();
        int myd = sh_deg[t];
        sh_ts[t] = myd;
        __syncthreads();
        for (int d = 1; d < 256; d <<= 1) {
            int x = (t >= d) ? sh_ts[t - d] : 0;
            __syncthreads();
            sh_ts[t] += x;
            __syncthreads();
        }
        int st_ = e0 + sh_ts[t] - myd;   // segment start
        __syncthreads();
        sh_deg[t] = st_;                 // cur
        if (t < ncnt) off[nbase + t] = st_ + myd;   // segment END
        __syncthreads();
        for (int e = e0 + t; e < e1; e += 256) {
            int2 p = binE[e];
            int r = atomicAdd(&sh_deg[p.y - nbase], 1);
            csr[r] = p.x;
        }
    }
}

// ---------------- k_host: G2+G3 fused (M=20000), 512 thr, col-split waves ----------------
__global__ __launch_bounds__(512, 4) void k_host(
    const u16* __restrict__ xfb, const u16* __restrict__ xhb,
    const int* __restrict__ off, const int* __restrict__ csr,
    const u16* __restrict__ WT0, const float* __restrict__ b0,
    const u16* __restrict__ WT1l, u16* __restrict__ hT, int M) {
    __shared__ __align__(16) u16 sA[64 * 136];
    __shared__ int sOff[72];
    __shared__ int sCsr[2560];
    const int t = threadIdx.x;
    const int m0 = blockIdx.x * 64;
    if (t < 65) {
        int idx = N_FLOW + m0 - 1 + t;
        sOff[t] = off[min(idx, NSEG - 1)];
    }
    // direct half: xhb row, k in [64,128)  — 512 chunks, 1/thread
    {
        int r = t >> 3, c = t & 7;
        int row = m0 + r;
        uint4 v = make_uint4(0u, 0u, 0u, 0u);
        if (row < M) v = *(const uint4*)(xhb + row * 64 + c * 8);
        *(uint4*)(&sA[r * 136 + 64 + c * 8]) = v;
    }
    __syncthreads();
    int st0 = sOff[0];
    int win = sOff[64] - st0;
    bool fit = (win <= 2560);
    if (fit) for (int e = t; e < win; e += 512) sCsr[e] = csr[st0 + e];
    __syncthreads();
    // gather half: mean(xfb nbrs), k in [0,64) — deg~30, batch 8 loads/round
    {
        int r = t >> 3, c = t & 7;
        int row = m0 + r;
        uint4 o = make_uint4(0u, 0u, 0u, 0u);
        if (row < M) o = gmean<8>(xfb, 64, c * 8, csr, sCsr, st0, fit, sOff[r], sOff[r + 1]);
        *(uint4*)(&sA[r * 136 + c * 8]) = o;
    }
    __syncthreads();
    const int w = t >> 6, wr = w >> 1, wc = w & 1;
    const int ln = t & 63, l15 = ln & 15, quad = ln >> 4;
    const u16* pA = sA + (wr * 16 + l15) * 136 + quad * 8;
    const u16* pB0 = WT0 + wc * 8192 + l15 * 128 + quad * 8;
    f32x4 acc[4];
#pragma unroll
    for (int tt = 0; tt < 4; tt++) acc[tt] = (f32x4){0.f, 0.f, 0.f, 0.f};
#pragma unroll
    for (int s = 0; s < 4; s++) {
        bf16x8 a = *(const bf16x8*)(pA + s * 32);
#pragma unroll
        for (int tt = 0; tt < 4; tt++) {
            bf16x8 b = *(const bf16x8*)(pB0 + tt * 2048 + s * 32);
            acc[tt] = __builtin_amdgcn_mfma_f32_16x16x32_bf16(a, b, acc[tt], 0, 0, 0);
        }
    }
    __syncthreads();   // all phase-A reads of sA done before h overwrites it
#pragma unroll
    for (int tt = 0; tt < 4; tt++) {
        int col = wc * 64 + tt * 16 + l15;
        float bv = b0[col];
#pragma unroll
        for (int i = 0; i < 4; i++) {
            int rl = wr * 16 + quad * 4 + i;
            float v = acc[tt][i] + bv;
            v = v > 0.f ? v : 0.01f * v;
            sA[rl * 136 + col] = fbh(v);
        }
    }
    __syncthreads();   // h complete (both col-half waves) before phase B reads
    const u16* pB1 = WT1l + wc * 8192 + l15 * 128 + quad * 8;
    f32x4 accB[4];
#pragma unroll
    for (int tt = 0; tt < 4; tt++) accB[tt] = (f32x4){0.f, 0.f, 0.f, 0.f};
#pragma unroll
    for (int s = 0; s < 4; s++) {
        bf16x8 a = *(const bf16x8*)(pA + s * 32);
#pragma unroll
        for (int tt = 0; tt < 4; tt++) {
            bf16x8 b = *(const bf16x8*)(pB1 + tt * 2048 + s * 32);
            accB[tt] = __builtin_amdgcn_mfma_f32_16x16x32_bf16(a, b, accB[tt], 0, 0, 0);
        }
    }
#pragma unroll
    for (int tt = 0; tt < 4; tt++) {
        int col = wc * 64 + tt * 16 + l15;
#pragma unroll
        for (int i = 0; i < 4; i++) {
            int row = m0 + wr * 16 + quad * 4 + i;
            if (row < M) hT[row * D_H + col] = fbh(accB[tt][i]);
        }
    }
}

// ---- k_mega: G1+G4 fused (M=200000) — R9 structure + non-temporal streaming ----
__global__ __launch_bounds__(512, 8) void k_mega(
    const u16* __restrict__ xfb, const u16* __restrict__ xhb,
    const int* __restrict__ off, const int* __restrict__ csr,
    const u16* __restrict__ hT,
    const u16* __restrict__ WT0, const float* __restrict__ b0,
    const u16* __restrict__ WT1r, const float* __restrict__ b1,
    const u16* __restrict__ WTo, const float* __restrict__ bout,
    float* __restrict__ OUT) {
    __shared__ __align__(16) u16 sA[64 * 136];    // A0 tile -> h band
    __shared__ __align__(16) u16 sAg[64 * 136];   // gathered mean(hT) tile -> g band
    __shared__ int sOff[72];
    __shared__ int sCsr[1024];
    const int t = threadIdx.x;
    const int m0 = blockIdx.x * 64;
    if (t < 65) {
        int idx = m0 - 1 + t;
        sOff[t] = (idx < 0) ? 0 : off[idx];
    }
    // direct half: xfb row, k in [64,128) — streaming (read-once): non-temporal
    {
        int r = t >> 3, c = t & 7;
        const u32x4* p = (const u32x4*)(xfb + (m0 + r) * 64 + c * 8);
        u32x4 v = __builtin_nontemporal_load(p);
        *(u32x4*)(&sA[r * 136 + 64 + c * 8]) = v;
    }
    __syncthreads();
    int st0 = sOff[0];
    int win = sOff[64] - st0;
    bool fit = (win <= 1024);
    if (fit) for (int e = t; e < win; e += 512)
        sCsr[e] = __builtin_nontemporal_load(csr + st0 + e);   // read-once stream
    __syncthreads();
    // A0 gather half: mean(xhb nbrs), k in [0,64) — 512 tasks
    {
        int r = t >> 3, c = t & 7;
        uint4 o = gmean<4>(xhb, 64, c * 8, csr, sCsr, st0, fit, sOff[r], sOff[r + 1]);
        *(uint4*)(&sA[r * 136 + c * 8]) = o;
    }
    // agg tile: mean(hT nbrs), 128d — 1024 tasks, 2/thread
#pragma unroll
    for (int i = 0; i < 2; i++) {
        int q = t + i * 512;
        int r = q >> 4, c = q & 15;
        uint4 o = gmean<4>(hT, 128, c * 8, csr, sCsr, st0, fit, sOff[r], sOff[r + 1]);
        *(uint4*)(&sAg[r * 136 + c * 8]) = o;
    }
    __syncthreads();
    const int w = t >> 6, wr = w >> 1, wc = w & 1;   // wave = (row-band, col-half)
    const int ln = t & 63, l15 = ln & 15, quad = ln >> 4;
    const u16* pA = sA + (wr * 16 + l15) * 136 + quad * 8;
    const u16* pB0 = WT0 + wc * 8192 + l15 * 128 + quad * 8;
    f32x4 acc[4];
#pragma unroll
    for (int tt = 0; tt < 4; tt++) acc[tt] = (f32x4){0.f, 0.f, 0.f, 0.f};
#pragma unroll
    for (int s = 0; s < 4; s++) {
        bf16x8 av = *(const bf16x8*)(pA + s * 32);
#pragma unroll
        for (int tt = 0; tt < 4; tt++) {
            bf16x8 b = *(const bf16x8*)(pB0 + tt * 2048 + s * 32);
            acc[tt] = __builtin_amdgcn_mfma_f32_16x16x32_bf16(av, b, acc[tt], 0, 0, 0);
        }
    }
    __syncthreads();   // all phase-A reads of sA done before h overwrites it
    // epilogue1: h = lrelu(acc + b0) -> sA band (cols wc*64 ..)
#pragma unroll
    for (int tt = 0; tt < 4; tt++) {
        int col = wc * 64 + tt * 16 + l15;
        float bv = b0[col];
#pragma unroll
        for (int i = 0; i < 4; i++) {
            int rl = wr * 16 + quad * 4 + i;
            float v = acc[tt][i] + bv;
            v = v > 0.f ? v : 0.01f * v;
            sA[rl * 136 + col] = fbh(v);
        }
    }
    __syncthreads();   // h complete before phase B reads full rows
    // phase B: h @ WT1r^T
    const u16* pB1 = WT1r + wc * 8192 + l15 * 128 + quad * 8;
    f32x4 accB[4];
#pragma unroll
    for (int tt = 0; tt < 4; tt++) accB[tt] = (f32x4){0.f, 0.f, 0.f, 0.f};
#pragma unroll
    for (int s = 0; s < 4; s++) {
        bf16x8 av = *(const bf16x8*)(pA + s * 32);
#pragma unroll
        for (int tt = 0; tt < 4; tt++) {
            bf16x8 b = *(const bf16x8*)(pB1 + tt * 2048 + s * 32);
            accB[tt] = __builtin_amdgcn_mfma_f32_16x16x32_bf16(av, b, accB[tt], 0, 0, 0);
        }
    }
    // epilogue2: g = lrelu(accB + agg + b1) -> in-place over sAg
#pragma unroll
    for (int tt = 0; tt < 4; tt++) {
        int col = wc * 64 + tt * 16 + l15;
        float bv = b1[col];
#pragma unroll
        for (int i = 0; i < 4; i++) {
            int rl = wr * 16 + quad * 4 + i;
            float v = accB[tt][i] + bfh(sAg[rl * 136 + col]) + bv;
            v = v > 0.f ? v : 0.01f * v;
            sAg[rl * 136 + col] = fbh(v);
        }
    }
    __syncthreads();   // g complete before phase C reads full rows
    // phase C: out = g @ WTo^T + bout  (each wave: 16-row band x 16-col tile wc)
    const u16* pG = sAg + (wr * 16 + l15) * 136 + quad * 8;
    const u16* pBo = WTo + wc * 2048 + l15 * 128 + quad * 8;
    f32x4 acc2 = (f32x4){0.f, 0.f, 0.f, 0.f};
#pragma unroll
    for (int s = 0; s < 4; s++) {
        bf16x8 g = *(const bf16x8*)(pG + s * 32);
        bf16x8 b = *(const bf16x8*)(pBo + s * 32);
        acc2 = __builtin_amdgcn_mfma_f32_16x16x32_bf16(g, b, acc2, 0, 0, 0);
    }
    {
        int col = wc * 16 + l15;
        float bv = bout[col];
#pragma unroll
        for (int i = 0; i < 4; i++) {
            int row = m0 + wr * 16 + quad * 4 + i;
            __builtin_nontemporal_store(acc2[i] + bv, &OUT[row * D_OUT + col]);
        }
    }
}

extern "C" void kernel_launch(void* const* d_in, const int* in_sizes, int n_in,
                              void* d_out, int out_size, void* d_ws, size_t ws_size,
                              hipStream_t stream) {
    const float* x_host  = (const float*)d_in[0];
    const float* x_flow  = (const float*)d_in[1];
    const int* src_hf  = (const int*)d_in[2];
    const int* dst_hf  = (const int*)d_in[3];
    const int* src_fh  = (const int*)d_in[4];
    const int* dst_fh  = (const int*)d_in[5];
    const float* W0_hf_l = (const float*)d_in[6];
    const float* W0_hf_r = (const float*)d_in[7];
    const float* b0_hf   = (const float*)d_in[8];
    const float* W0_fh_l = (const float*)d_in[9];
    const float* W0_fh_r = (const float*)d_in[10];
    const float* b0_fh   = (const float*)d_in[11];
    const float* W1_hf_l = (const float*)d_in[12];
    const float* W1_hf_r = (const float*)d_in[13];
    const float* b1_hf   = (const float*)d_in[14];
    const float* W_out   = (const float*)d_in[18];
    const float* b_out   = (const float*)d_in[19];
    float* out = (float*)d_out;

    // workspace layout (bytes), total ~48.7 MB (unchanged footprint)
    char* ws = (char*)d_ws;
    int*  off    = (int*)(ws + 0);             //   880,000
    int*  csr    = (int*)(ws + 880000);        // 4,800,000
    u16*  hT     = (u16*)(ws + 5680000);       // 5,120,000  (written by k_host)
    int*  bcnt   = (int*)(ws + 5680000);       //     4,380 } alias hT region:
    int*  bcur   = (int*)(ws + 5684380);       //     4,380 } dead before k_host
    u16*  xfb    = (u16*)(ws + 10800000);      // 25,600,000
    u16*  xhb    = (u16*)(ws + 36400000);      //  2,560,000
    int2* binE   = (int2*)(ws + 38960000);     //  9,600,000
    u16*  WT0_hf = (u16*)(ws + 48562560);      //  32,768
    u16*  WT0_fh = (u16*)(ws + 48595328);      //  32,768
    u16*  WT1_l  = (u16*)(ws + 48628096);      //  32,768
    u16*  WT1_r  = (u16*)(ws + 48660864);      //  32,768
    u16*  WTo    = (u16*)(ws + 48693632);      //   8,192

    k_pre<<<34 + 6875, 256, 0, stream>>>(
        W0_hf_l, W0_hf_r, W0_fh_l, W0_fh_r, W1_hf_l, W1_hf_r, W_out,
        WT0_hf, WT0_fh, WT1_l, WT1_r, WTo,
        x_flow, x_host, xfb, xhb);
    {
        void* kargs[] = {(void*)&src_hf, (void*)&dst_hf, (void*)&src_fh, (void*)&dst_fh,
                         (void*)&bcnt, (void*)&bcur, (void*)&binE, (void*)&off,
                         (void*)&csr};
        (void)hipLaunchCooperativeKernel((const void*)k_graph, dim3(NBKT), dim3(256),
                                         kargs, 0, stream);
    }
    k_host<<<313, 512, 0, stream>>>(xfb, xhb, off, csr, WT0_fh, b0_fh, WT1_l, hT, N_HOST);
    k_mega<<<3125, 512, 0, stream>>>(xfb, xhb, off, csr, hT, WT0_hf, b0_hf,
                                     WT1_r, b1_hf, WTo, b_out, out);
}

// Round 14
// 338.616 us; speedup vs baseline: 2.6501x; 2.6501x over previous
//
#include <hip/hip_runtime.h>

// HeteroGNN on MI355X. Inputs/weights/output fp32 (per reference); intermediates bf16.
// Round 22 = exact revert to R20 (best measured: 336.3us).
//  - R21 post-mortem: cooperative fusion DISASTER (k_graph 585us alone, VALUBusy
//    0.6%): grid.sync on 8-XCD MI355X needs device-scope coherence across
//    non-coherent L2s, ~100+us per sync x4. Launch-fusion path dead on this HW.
//  - Session state: k_mega at 4x-confirmed structural floor (~136us; TLP/VALU/ILP/L2
//    experiments all null). Rest ~200us over 5 small dependent dispatches, each
//    within ~2x of BW/latency floor. This revert re-establishes the known-good best.
//   k_pre  : weights->bf16 WT[n][k] | x->bf16 pools | bucket histogram
//   kb2    : bin scatter (in-block 1095-prefix)  kb3: per-bucket CSR build
//   k_host : h=lrelu([mean(xfb nbrs)|xhb]@WT0_fh^T+b0); hT=h@WT1_l^T        (M=20000)
//   k_mega : h=lrelu([mean(xhb nbrs)|xfb]@WT0_hf^T+b0);
//            g=lrelu(h@WT1_r^T+mean(hT nbrs)+b1); out=g@WTo^T+bout          (M=200000)
// g_host dead in reference -> W1_fh_* unused.

#define N_HOST 20000
#define N_FLOW 200000
#define NEDGE  600000
#define D_IN   64
#define D_H    128
#define D_OUT  32
#define NSEG   (N_FLOW + N_HOST)
#define NBKT_F 782                 // 256-node flow buckets (200000 -> 781*256+64)
#define NBKT_H 313                 // 64-node host buckets  (20000  -> 312*64+32)
#define NBKT   (NBKT_F + NBKT_H)   // 1095
#define NBKT_PAD 1100              // 5*220, scan padding
#define NEB    586                 // ceil(1200000/2048)

typedef unsigned short u16;
typedef unsigned int   u32;
typedef short bf16x8 __attribute__((ext_vector_type(8)));
typedef float f32x4  __attribute__((ext_vector_type(4)));
typedef float fx2    __attribute__((ext_vector_type(2)));
typedef unsigned int u32x4 __attribute__((ext_vector_type(4)));   // for nontemporal ld

__device__ __forceinline__ float bfh(u16 h) { return __uint_as_float(((u32)h) << 16); }
__device__ __forceinline__ u16 fbh(float f) {
    u32 u = __float_as_uint(f);
    return (u16)((u + 0x7fffu + ((u >> 16) & 1u)) >> 16);   // RNE
}
__device__ __forceinline__ u32 packbf(float x, float y) {
    return (u32)fbh(x) | ((u32)fbh(y) << 16);
}
// packed bf16 unpack+accumulate (v_pk_add_f32)
__device__ __forceinline__ void accp(fx2* a, uint4 u) {
    fx2 p;
    p.x = __uint_as_float(u.x << 16); p.y = __uint_as_float(u.x & 0xffff0000u); a[0] += p;
    p.x = __uint_as_float(u.y << 16); p.y = __uint_as_float(u.y & 0xffff0000u); a[1] += p;
    p.x = __uint_as_float(u.z << 16); p.y = __uint_as_float(u.z & 0xffff0000u); a[2] += p;
    p.x = __uint_as_float(u.w << 16); p.y = __uint_as_float(u.w & 0xffff0000u); a[3] += p;
}
__device__ __forceinline__ uint4 packp(const fx2* a, float inv) {
    uint4 o;
    o.x = packbf(a[0].x * inv, a[0].y * inv);
    o.y = packbf(a[1].x * inv, a[1].y * inv);
    o.z = packbf(a[2].x * inv, a[2].y * inv);
    o.w = packbf(a[3].x * inv, a[3].y * inv);
    return o;
}

// gather-mean of 16B chunks; neighbor indices from LDS window (fit) or global fallback.
template <int U>
__device__ __forceinline__ uint4 gmean(const u16* __restrict__ pool, int rs, int coff,
                                       const int* __restrict__ gcsr,
                                       const int* __restrict__ lcsr, int st0, bool fit,
                                       int st, int en) {
    fx2 a[4] = {};
    for (int e = st; e < en; e += U) {
        int n[U];
#pragma unroll
        for (int j = 0; j < U; j++)
            n[j] = (e + j < en) ? (fit ? lcsr[e + j - st0] : gcsr[e + j]) : -1;
        uint4 u[U];
#pragma unroll
        for (int j = 0; j < U; j++)
            u[j] = (n[j] >= 0) ? *(const uint4*)(pool + n[j] * rs + coff)
                               : make_uint4(0u, 0u, 0u, 0u);
#pragma unroll
        for (int j = 0; j < U; j++) accp(a, u[j]);
    }
    float inv = (en > st) ? 1.f / (float)(en - st) : 0.f;
    return packp(a, inv);
}

// ---------------- k_pre: weights transpose | x->bf16 | bucket histogram ----------------
__global__ void k_pre(const float* __restrict__ W0_hf_l, const float* __restrict__ W0_hf_r,
                      const float* __restrict__ W0_fh_l, const float* __restrict__ W0_fh_r,
                      const float* __restrict__ W1_l, const float* __restrict__ W1_r,
                      const float* __restrict__ Wout,
                      u16* __restrict__ WT0_hf, u16* __restrict__ WT0_fh,
                      u16* __restrict__ WT1_l, u16* __restrict__ WT1_r,
                      u16* __restrict__ WTo,
                      const float* __restrict__ xf, const float* __restrict__ xh,
                      u16* __restrict__ xfb, u16* __restrict__ xhb,
                      const int* __restrict__ dst_hf, const int* __restrict__ dst_fh,
                      int* __restrict__ bcnt) {
    int b = blockIdx.x, t = threadIdx.x;
    if (b < 34) {
        u16 tmp[8];
        if (b < 32) {
            int e = (b & 7) * 2048 + t * 8;
            int n = e >> 7, k0 = e & 127;
            if (b < 8) {
#pragma unroll
                for (int j = 0; j < 8; j++) {
                    int k = k0 + j;
                    tmp[j] = fbh(k < 64 ? W0_hf_l[k * D_H + n] : W0_hf_r[(k - 64) * D_H + n]);
                }
                *(uint4*)(WT0_hf + n * 128 + k0) = *(uint4*)tmp;
            } else if (b < 16) {
#pragma unroll
                for (int j = 0; j < 8; j++) {
                    int k = k0 + j;
                    tmp[j] = fbh(k < 64 ? W0_fh_l[k * D_H + n] : W0_fh_r[(k - 64) * D_H + n]);
                }
                *(uint4*)(WT0_fh + n * 128 + k0) = *(uint4*)tmp;
            } else if (b < 24) {
#pragma unroll
                for (int j = 0; j < 8; j++) tmp[j] = fbh(W1_l[(k0 + j) * D_H + n]);
                *(uint4*)(WT1_l + n * 128 + k0) = *(uint4*)tmp;
            } else {
#pragma unroll
                for (int j = 0; j < 8; j++) tmp[j] = fbh(W1_r[(k0 + j) * D_H + n]);
                *(uint4*)(WT1_r + n * 128 + k0) = *(uint4*)tmp;
            }
        } else {
            int e = (b - 32) * 2048 + t * 8;
            int n = e >> 7, k0 = e & 127;
#pragma unroll
            for (int j = 0; j < 8; j++) tmp[j] = fbh(Wout[(k0 + j) * D_OUT + n]);
            *(uint4*)(WTo + n * 128 + k0) = *(uint4*)tmp;
        }
    } else if (b < 34 + 6875) {
        int q = (b - 34) * 256 + t;       // 8 floats per thread
        const int TF = (N_FLOW * D_IN) / 8;
        const int TT = TF + (N_HOST * D_IN) / 8;
        if (q >= TT) return;
        const float* src; u16* dst; int base;
        if (q < TF) { src = xf; dst = xfb; base = q * 8; }
        else        { src = xh; dst = xhb; base = (q - TF) * 8; }
        float4 f0 = *(const float4*)(src + base);
        float4 f1 = *(const float4*)(src + base + 4);
        uint4 o;
        o.x = packbf(f0.x, f0.y); o.y = packbf(f0.z, f0.w);
        o.z = packbf(f1.x, f1.y); o.w = packbf(f1.z, f1.w);
        *(uint4*)(dst + base) = o;
    } else {
        __shared__ int h[NBKT];
        for (int j = t; j < NBKT; j += 256) h[j] = 0;
        __syncthreads();
        int base = (b - 34 - 6875) * 2048;
#pragma unroll
        for (int i = 0; i < 8; i++) {
            int e = base + t + i * 256;
            if (e < 2 * NEDGE) {
                int bkt = (e < NEDGE) ? (dst_hf[e] >> 8)
                                      : (NBKT_F + (dst_fh[e - NEDGE] >> 6));
                atomicAdd(&h[bkt], 1);
            }
        }
        __syncthreads();
        for (int j = t; j < NBKT; j += 256)
            if (h[j]) atomicAdd(&bcnt[j], h[j]);
    }
}

// ---------------- kb2: bin scatter (in-block 1095-prefix of bcnt) ----------------
__global__ __launch_bounds__(256) void kb2(
    const int* __restrict__ src_hf, const int* __restrict__ dst_hf,
    const int* __restrict__ src_fh, const int* __restrict__ dst_fh,
    const int* __restrict__ bcnt, int* __restrict__ bcur,
    int2* __restrict__ binE) {
    __shared__ int spx[NBKT_PAD];   // exclusive bucket base
    __shared__ int ts[256];
    __shared__ int lh[NBKT];
    __shared__ int lb[NBKT];
    int t = threadIdx.x;
    // 5-per-thread 2-level exclusive scan of bcnt[0..NBKT)
    int v[5], loc[5];
    int b5 = t * 5, s = 0;
#pragma unroll
    for (int j = 0; j < 5; j++) {
        int idx = b5 + j;
        v[j] = (idx < NBKT) ? bcnt[idx] : 0;
        loc[j] = s; s += v[j];
    }
    ts[t] = s;
    for (int j = t; j < NBKT; j += 256) lh[j] = 0;
    __syncthreads();
    for (int d = 1; d < 256; d <<= 1) {
        int x = (t >= d) ? ts[t - d] : 0;
        __syncthreads();
        ts[t] += x;
        __syncthreads();
    }
    int ex = ts[t] - s;
#pragma unroll
    for (int j = 0; j < 5; j++) {
        int idx = b5 + j;
        if (idx < NBKT_PAD) spx[idx] = ex + loc[j];
    }
    __syncthreads();
    int base = blockIdx.x * 2048;
    int mybkt[8], myrank[8], mysrc[8], mydst[8];
#pragma unroll
    for (int i = 0; i < 8; i++) {
        int e = base + t + i * 256;
        mybkt[i] = -1;
        if (e < 2 * NEDGE) {
            int sv, d;
            if (e < NEDGE) { sv = src_hf[e]; d = dst_hf[e]; }
            else           { sv = src_fh[e - NEDGE]; d = dst_fh[e - NEDGE] + N_FLOW; }
            int bkt = (d < N_FLOW) ? (d >> 8) : (NBKT_F + ((d - N_FLOW) >> 6));
            mybkt[i] = bkt; mysrc[i] = sv; mydst[i] = d;
            myrank[i] = atomicAdd(&lh[bkt], 1);
        }
    }
    __syncthreads();
    for (int j = t; j < NBKT; j += 256)
        lb[j] = lh[j] ? atomicAdd(&bcur[j], lh[j]) : 0;
    __syncthreads();
#pragma unroll
    for (int i = 0; i < 8; i++) {
        if (mybkt[i] >= 0) {
            int pos = spx[mybkt[i]] + lb[mybkt[i]] + myrank[i];
            binE[pos] = make_int2(mysrc[i], mydst[i]);
        }
    }
}

// ------- kb3: per-bucket CSR build (1095 blocks, 256/64-node buckets) -------
__global__ __launch_bounds__(256) void kb3(const int2* __restrict__ binE,
                                           const int* __restrict__ bcnt,
                                           int* __restrict__ off, int* __restrict__ csr) {
    __shared__ int sinc[NBKT_PAD];   // inclusive bucket prefix
    __shared__ int ts[256];
    __shared__ int deg[256];
    int b = blockIdx.x, t = threadIdx.x;
    // 5-per-thread 2-level inclusive scan of bcnt
    int v[5], iv[5];
    int b5 = t * 5, s = 0;
#pragma unroll
    for (int j = 0; j < 5; j++) {
        int idx = b5 + j;
        v[j] = (idx < NBKT) ? bcnt[idx] : 0;
        s += v[j]; iv[j] = s;
    }
    ts[t] = s;
    __syncthreads();
    for (int d = 1; d < 256; d <<= 1) {
        int x = (t >= d) ? ts[t - d] : 0;
        __syncthreads();
        ts[t] += x;
        __syncthreads();
    }
    int ex = ts[t] - s;
#pragma unroll
    for (int j = 0; j < 5; j++) {
        int idx = b5 + j;
        if (idx < NBKT_PAD) sinc[idx] = ex + iv[j];
    }
    deg[t] = 0;
    __syncthreads();
    int e0 = (b == 0) ? 0 : sinc[b - 1];
    int e1 = sinc[b];
    int nbase, ncnt;
    if (b < NBKT_F) { nbase = b << 8; ncnt = min(256, N_FLOW - nbase); }
    else { int hb = b - NBKT_F; nbase = N_FLOW + (hb << 6); ncnt = min(64, NSEG - nbase); }
    for (int e = e0 + t; e < e1; e += 256) {
        int2 p = binE[e];
        atomicAdd(&deg[p.y - nbase], 1);
    }
    __syncthreads();
    int myd = deg[t];
    ts[t] = myd;
    __syncthreads();
    for (int d = 1; d < 256; d <<= 1) {
        int x = (t >= d) ? ts[t - d] : 0;
        __syncthreads();
        ts[t] += x;
        __syncthreads();
    }
    int st_ = e0 + ts[t] - myd;   // segment start
    __syncthreads();
    deg[t] = st_;                 // cur
    if (t < ncnt) off[nbase + t] = st_ + myd;   // segment END
    __syncthreads();
    for (int e = e0 + t; e < e1; e += 256) {
        int2 p = binE[e];
        int r = atomicAdd(&deg[p.y - nbase], 1);
        csr[r] = p.x;
    }
}

// ---------------- k_host: G2+G3 fused (M=20000), 512 thr, col-split waves ----------------
__global__ __launch_bounds__(512, 4) void k_host(
    const u16* __restrict__ xfb, const u16* __restrict__ xhb,
    const int* __restrict__ off, const int* __restrict__ csr,
    const u16* __restrict__ WT0, const float* __restrict__ b0,
    const u16* __restrict__ WT1l, u16* __restrict__ hT, int M) {
    __shared__ __align__(16) u16 sA[64 * 136];
    __shared__ int sOff[72];
    __shared__ int sCsr[2560];
    const int t = threadIdx.x;
    const int m0 = blockIdx.x * 64;
    if (t < 65) {
        int idx = N_FLOW + m0 - 1 + t;
        sOff[t] = off[min(idx, NSEG - 1)];
    }
    // direct half: xhb row, k in [64,128)  — 512 chunks, 1/thread
    {
        int r = t >> 3, c = t & 7;
        int row = m0 + r;
        uint4 v = make_uint4(0u, 0u, 0u, 0u);
        if (row < M) v = *(const uint4*)(xhb + row * 64 + c * 8);
        *(uint4*)(&sA[r * 136 + 64 + c * 8]) = v;
    }
    __syncthreads();
    int st0 = sOff[0];
    int win = sOff[64] - st0;
    bool fit = (win <= 2560);
    if (fit) for (int e = t; e < win; e += 512) sCsr[e] = csr[st0 + e];
    __syncthreads();
    // gather half: mean(xfb nbrs), k in [0,64) — deg~30, batch 8 loads/round
    {
        int r = t >> 3, c = t & 7;
        int row = m0 + r;
        uint4 o = make_uint4(0u, 0u, 0u, 0u);
        if (row < M) o = gmean<8>(xfb, 64, c * 8, csr, sCsr, st0, fit, sOff[r], sOff[r + 1]);
        *(uint4*)(&sA[r * 136 + c * 8]) = o;
    }
    __syncthreads();
    const int w = t >> 6, wr = w >> 1, wc = w & 1;
    const int ln = t & 63, l15 = ln & 15, quad = ln >> 4;
    const u16* pA = sA + (wr * 16 + l15) * 136 + quad * 8;
    const u16* pB0 = WT0 + wc * 8192 + l15 * 128 + quad * 8;
    f32x4 acc[4];
#pragma unroll
    for (int tt = 0; tt < 4; tt++) acc[tt] = (f32x4){0.f, 0.f, 0.f, 0.f};
#pragma unroll
    for (int s = 0; s < 4; s++) {
        bf16x8 a = *(const bf16x8*)(pA + s * 32);
#pragma unroll
        for (int tt = 0; tt < 4; tt++) {
            bf16x8 b = *(const bf16x8*)(pB0 + tt * 2048 + s * 32);
            acc[tt] = __builtin_amdgcn_mfma_f32_16x16x32_bf16(a, b, acc[tt], 0, 0, 0);
        }
    }
    __syncthreads();   // all phase-A reads of sA done before h overwrites it
#pragma unroll
    for (int tt = 0; tt < 4; tt++) {
        int col = wc * 64 + tt * 16 + l15;
        float bv = b0[col];
#pragma unroll
        for (int i = 0; i < 4; i++) {
            int rl = wr * 16 + quad * 4 + i;
            float v = acc[tt][i] + bv;
            v = v > 0.f ? v : 0.01f * v;
            sA[rl * 136 + col] = fbh(v);
        }
    }
    __syncthreads();   // h complete (both col-half waves) before phase B reads
    const u16* pB1 = WT1l + wc * 8192 + l15 * 128 + quad * 8;
    f32x4 accB[4];
#pragma unroll
    for (int tt = 0; tt < 4; tt++) accB[tt] = (f32x4){0.f, 0.f, 0.f, 0.f};
#pragma unroll
    for (int s = 0; s < 4; s++) {
        bf16x8 a = *(const bf16x8*)(pA + s * 32);
#pragma unroll
        for (int tt = 0; tt < 4; tt++) {
            bf16x8 b = *(const bf16x8*)(pB1 + tt * 2048 + s * 32);
            accB[tt] = __builtin_amdgcn_mfma_f32_16x16x32_bf16(a, b, accB[tt], 0, 0, 0);
        }
    }
#pragma unroll
    for (int tt = 0; tt < 4; tt++) {
        int col = wc * 64 + tt * 16 + l15;
#pragma unroll
        for (int i = 0; i < 4; i++) {
            int row = m0 + wr * 16 + quad * 4 + i;
            if (row < M) hT[row * D_H + col] = fbh(accB[tt][i]);
        }
    }
}

// ---- k_mega: G1+G4 fused (M=200000) — R9 structure + non-temporal streaming ----
__global__ __launch_bounds__(512, 8) void k_mega(
    const u16* __restrict__ xfb, const u16* __restrict__ xhb,
    const int* __restrict__ off, const int* __restrict__ csr,
    const u16* __restrict__ hT,
    const u16* __restrict__ WT0, const float* __restrict__ b0,
    const u16* __restrict__ WT1r, const float* __restrict__ b1,
    const u16* __restrict__ WTo, const float* __restrict__ bout,
    float* __restrict__ OUT) {
    __shared__ __align__(16) u16 sA[64 * 136];    // A0 tile -> h band
    __shared__ __align__(16) u16 sAg[64 * 136];   // gathered mean(hT) tile -> g band
    __shared__ int sOff[72];
    __shared__ int sCsr[1024];
    const int t = threadIdx.x;
    const int m0 = blockIdx.x * 64;
    if (t < 65) {
        int idx = m0 - 1 + t;
        sOff[t] = (idx < 0) ? 0 : off[idx];
    }
    // direct half: xfb row, k in [64,128) — streaming (read-once): non-temporal
    {
        int r = t >> 3, c = t & 7;
        const u32x4* p = (const u32x4*)(xfb + (m0 + r) * 64 + c * 8);
        u32x4 v = __builtin_nontemporal_load(p);
        *(u32x4*)(&sA[r * 136 + 64 + c * 8]) = v;
    }
    __syncthreads();
    int st0 = sOff[0];
    int win = sOff[64] - st0;
    bool fit = (win <= 1024);
    if (fit) for (int e = t; e < win; e += 512)
        sCsr[e] = __builtin_nontemporal_load(csr + st0 + e);   // read-once stream
    __syncthreads();
    // A0 gather half: mean(xhb nbrs), k in [0,64) — 512 tasks
    {
        int r = t >> 3, c = t & 7;
        uint4 o = gmean<4>(xhb, 64, c * 8, csr, sCsr, st0, fit, sOff[r], sOff[r + 1]);
        *(uint4*)(&sA[r * 136 + c * 8]) = o;
    }
    // agg tile: mean(hT nbrs), 128d — 1024 tasks, 2/thread
#pragma unroll
    for (int i = 0; i < 2; i++) {
        int q = t + i * 512;
        int r = q >> 4, c = q & 15;
        uint4 o = gmean<4>(hT, 128, c * 8, csr, sCsr, st0, fit, sOff[r], sOff[r + 1]);
        *(uint4*)(&sAg[r * 136 + c * 8]) = o;
    }
    __syncthreads();
    const int w = t >> 6, wr = w >> 1, wc = w & 1;   // wave = (row-band, col-half)
    const int ln = t & 63, l15 = ln & 15, quad = ln >> 4;
    const u16* pA = sA + (wr * 16 + l15) * 136 + quad * 8;
    const u16* pB0 = WT0 + wc * 8192 + l15 * 128 + quad * 8;
    f32x4 acc[4];
#pragma unroll
    for (int tt = 0; tt < 4; tt++) acc[tt] = (f32x4){0.f, 0.f, 0.f, 0.f};
#pragma unroll
    for (int s = 0; s < 4; s++) {
        bf16x8 av = *(const bf16x8*)(pA + s * 32);
#pragma unroll
        for (int tt = 0; tt < 4; tt++) {
            bf16x8 b = *(const bf16x8*)(pB0 + tt * 2048 + s * 32);
            acc[tt] = __builtin_amdgcn_mfma_f32_16x16x32_bf16(av, b, acc[tt], 0, 0, 0);
        }
    }
    __syncthreads();   // all phase-A reads of sA done before h overwrites it
    // epilogue1: h = lrelu(acc + b0) -> sA band (cols wc*64 ..)
#pragma unroll
    for (int tt = 0; tt < 4; tt++) {
        int col = wc * 64 + tt * 16 + l15;
        float bv = b0[col];
#pragma unroll
        for (int i = 0; i < 4; i++) {
            int rl = wr * 16 + quad * 4 + i;
            float v = acc[tt][i] + bv;
            v = v > 0.f ? v : 0.01f * v;
            sA[rl * 136 + col] = fbh(v);
        }
    }
    __syncthreads();   // h complete before phase B reads full rows
    // phase B: h @ WT1r^T
    const u16* pB1 = WT1r + wc * 8192 + l15 * 128 + quad * 8;
    f32x4 accB[4];
#pragma unroll
    for (int tt = 0; tt < 4; tt++) accB[tt] = (f32x4){0.f, 0.f, 0.f, 0.f};
#pragma unroll
    for (int s = 0; s < 4; s++) {
        bf16x8 av = *(const bf16x8*)(pA + s * 32);
#pragma unroll
        for (int tt = 0; tt < 4; tt++) {
            bf16x8 b = *(const bf16x8*)(pB1 + tt * 2048 + s * 32);
            accB[tt] = __builtin_amdgcn_mfma_f32_16x16x32_bf16(av, b, accB[tt], 0, 0, 0);
        }
    }
    // epilogue2: g = lrelu(accB + agg + b1) -> in-place over sAg
#pragma unroll
    for (int tt = 0; tt < 4; tt++) {
        int col = wc * 64 + tt * 16 + l15;
        float bv = b1[col];
#pragma unroll
        for (int i = 0; i < 4; i++) {
            int rl = wr * 16 + quad * 4 + i;
            float v = accB[tt][i] + bfh(sAg[rl * 136 + col]) + bv;
            v = v > 0.f ? v : 0.01f * v;
            sAg[rl * 136 + col] = fbh(v);
        }
    }
    __syncthreads();   // g complete before phase C reads full rows
    // phase C: out = g @ WTo^T + bout  (each wave: 16-row band x 16-col tile wc)
    const u16* pG = sAg + (wr * 16 + l15) * 136 + quad * 8;
    const u16* pBo = WTo + wc * 2048 + l15 * 128 + quad * 8;
    f32x4 acc2 = (f32x4){0.f, 0.f, 0.f, 0.f};
#pragma unroll
    for (int s = 0; s < 4; s++) {
        bf16x8 g = *(const bf16x8*)(pG + s * 32);
        bf16x8 b = *(const bf16x8*)(pBo + s * 32);
        acc2 = __builtin_amdgcn_mfma_f32_16x16x32_bf16(g, b, acc2, 0, 0, 0);
    }
    {
        int col = wc * 16 + l15;
        float bv = bout[col];
#pragma unroll
        for (int i = 0; i < 4; i++) {
            int row = m0 + wr * 16 + quad * 4 + i;
            __builtin_nontemporal_store(acc2[i] + bv, &OUT[row * D_OUT + col]);
        }
    }
}

extern "C" void kernel_launch(void* const* d_in, const int* in_sizes, int n_in,
                              void* d_out, int out_size, void* d_ws, size_t ws_size,
                              hipStream_t stream) {
    const float* x_host  = (const float*)d_in[0];
    const float* x_flow  = (const float*)d_in[1];
    const int* src_hf  = (const int*)d_in[2];
    const int* dst_hf  = (const int*)d_in[3];
    const int* src_fh  = (const int*)d_in[4];
    const int* dst_fh  = (const int*)d_in[5];
    const float* W0_hf_l = (const float*)d_in[6];
    const float* W0_hf_r = (const float*)d_in[7];
    const float* b0_hf   = (const float*)d_in[8];
    const float* W0_fh_l = (const float*)d_in[9];
    const float* W0_fh_r = (const float*)d_in[10];
    const float* b0_fh   = (const float*)d_in[11];
    const float* W1_hf_l = (const float*)d_in[12];
    const float* W1_hf_r = (const float*)d_in[13];
    const float* b1_hf   = (const float*)d_in[14];
    const float* W_out   = (const float*)d_in[18];
    const float* b_out   = (const float*)d_in[19];
    float* out = (float*)d_out;

    // workspace layout (bytes), total ~48.7 MB (unchanged footprint)
    char* ws = (char*)d_ws;
    int*  off    = (int*)(ws + 0);             //   880,000
    int*  csr    = (int*)(ws + 880000);        // 4,800,000
    u16*  hT     = (u16*)(ws + 5680000);       // 5,120,000  (written by k_host)
    int*  bcnt   = (int*)(ws + 5680000);       //     4,380 } alias hT region:
    int*  bcur   = (int*)(ws + 5684380);       //     4,380 } dead before k_host
    u16*  xfb    = (u16*)(ws + 10800000);      // 25,600,000
    u16*  xhb    = (u16*)(ws + 36400000);      //  2,560,000
    int2* binE   = (int2*)(ws + 38960000);     //  9,600,000
    u16*  WT0_hf = (u16*)(ws + 48562560);      //  32,768
    u16*  WT0_fh = (u16*)(ws + 48595328);      //  32,768
    u16*  WT1_l  = (u16*)(ws + 48628096);      //  32,768
    u16*  WT1_r  = (u16*)(ws + 48660864);      //  32,768
    u16*  WTo    = (u16*)(ws + 48693632);      //   8,192

    (void)hipMemsetAsync(bcnt, 0, 8760, stream);     // bcnt + bcur (contiguous)
    k_pre<<<34 + 6875 + NEB, 256, 0, stream>>>(
        W0_hf_l, W0_hf_r, W0_fh_l, W0_fh_r, W1_hf_l, W1_hf_r, W_out,
        WT0_hf, WT0_fh, WT1_l, WT1_r, WTo,
        x_flow, x_host, xfb, xhb, dst_hf, dst_fh, bcnt);
    kb2<<<NEB, 256, 0, stream>>>(src_hf, dst_hf, src_fh, dst_fh, bcnt, bcur, binE);
    kb3<<<NBKT, 256, 0, stream>>>(binE, bcnt, off, csr);
    k_host<<<313, 512, 0, stream>>>(xfb, xhb, off, csr, WT0_fh, b0_fh, WT1_l, hT, N_HOST);
    k_mega<<<3125, 512, 0, stream>>>(xfb, xhb, off, csr, hT, WT0_hf, b0_hf,
                                     WT1_r, b1_hf, WTo, b_out, out);
}